// Round 1
// baseline (396.170 us; speedup 1.0000x reference)
//
#include <hip/hip_runtime.h>
#include <hip/hip_bf16.h>
#include <stdint.h>

typedef __attribute__((ext_vector_type(8))) short short8v;    // 8 x bf16 (MFMA A/B frag)
typedef __attribute__((ext_vector_type(4))) float float4v;    // MFMA C/D frag / vec loads
typedef __attribute__((ext_vector_type(4))) unsigned short ushort4v;

#define FINF __builtin_huge_valf()
#define BB 64
#define NN 512
#define DD 256

// ws layout (bytes):
//   [0,        16777216)  xnb bf16 [B][N][D]
//   [16777216, 33554432)  ynb bf16 [B][N][D]
//   [33554432, 100663296) cost f32 [B][N][N]   (needs ws_size >= 96 MB)

static __device__ __forceinline__ unsigned short f2bf(float f) {
  union { float f; uint32_t u; } a; a.f = f;
  uint32_t r = a.u + 0x7fffu + ((a.u >> 16) & 1u);   // RNE
  return (unsigned short)(r >> 16);
}

// ---------------- Kernel 1: row-normalize + cast to bf16 ----------------
// 4 waves/block, one row per wave. rows [0,32768) -> x, [32768,65536) -> y.
__global__ __launch_bounds__(256) void norm_cast_kernel(
    const float* __restrict__ x, const float* __restrict__ y,
    uint16_t* __restrict__ xnb, uint16_t* __restrict__ ynb)
{
  const int wave = threadIdx.x >> 6, lane = threadIdx.x & 63;
  const int row = blockIdx.x * 4 + wave;
  const float* src; uint16_t* dst;
  if (row < BB * NN) { src = x + (size_t)row * DD;            dst = xnb + (size_t)row * DD; }
  else               { src = y + (size_t)(row - BB*NN) * DD;  dst = ynb + (size_t)(row - BB*NN) * DD; }
  const float4v v = *(const float4v*)(src + lane * 4);
  float s = v[0]*v[0] + v[1]*v[1] + v[2]*v[2] + v[3]*v[3];
  #pragma unroll
  for (int d = 1; d < 64; d <<= 1) s += __shfl_xor(s, d, 64);
  const float inv = 1.0f / fmaxf(sqrtf(s), 1e-8f);
  ushort4v o;
  o[0] = f2bf(v[0] * inv); o[1] = f2bf(v[1] * inv);
  o[2] = f2bf(v[2] * inv); o[3] = f2bf(v[3] * inv);
  *(ushort4v*)(dst + lane * 4) = o;
}

// ---------------- Kernel 2: cost[b,n,m] = 1 - xn[b,n,:]·yn[b,m,:] ----------------
// 128x128 tile per block, 4 waves (2x2), BK=32, K=256. NT-GEMM, bf16 MFMA 16x16x32.
__global__ __launch_bounds__(256) void gemm_cost_kernel(
    const uint16_t* __restrict__ xnb, const uint16_t* __restrict__ ynb,
    float* __restrict__ cost)
{
  __shared__ uint16_t As[128 * 32];
  __shared__ uint16_t Bs[128 * 32];
  const int bid = blockIdx.x;
  const int b = bid >> 4, tm = (bid >> 2) & 3, tn = bid & 3;
  const int tid = threadIdx.x, wave = tid >> 6, lane = tid & 63;
  const int wr = wave >> 1, wc = wave & 1;

  const char* Ab = (const char*)(xnb + (size_t)b * NN * DD + (size_t)tm * 128 * DD);
  const char* Bb = (const char*)(ynb + (size_t)b * NN * DD + (size_t)tn * 128 * DD);

  float4v acc[4][4];
  #pragma unroll
  for (int i = 0; i < 4; i++)
    #pragma unroll
    for (int j = 0; j < 4; j++) acc[i][j] = (float4v){0.f, 0.f, 0.f, 0.f};

  const int seg0 = wave * 2;
  const int o0 = seg0 * 1024 + lane * 16;  // byte offset in 8KB tile, instr 0
  const int o1 = o0 + 1024;                // instr 1
  const int r0 = o0 >> 6, c0 = o0 & 63;    // tile row / byte-in-row (64B = 32 bf16 = BK)
  const int r1 = o1 >> 6, c1 = o1 & 63;

  for (int kk = 0; kk < 8; kk++) {
    const int kb = kk * 64;  // K-offset in bytes (32 bf16)
    __builtin_amdgcn_global_load_lds(
        (const __attribute__((address_space(1))) uint32_t*)(Ab + (size_t)r0 * 512 + kb + c0),
        (__attribute__((address_space(3))) uint32_t*)((char*)As + seg0 * 1024), 16, 0, 0);
    __builtin_amdgcn_global_load_lds(
        (const __attribute__((address_space(1))) uint32_t*)(Ab + (size_t)r1 * 512 + kb + c1),
        (__attribute__((address_space(3))) uint32_t*)((char*)As + (seg0 + 1) * 1024), 16, 0, 0);
    __builtin_amdgcn_global_load_lds(
        (const __attribute__((address_space(1))) uint32_t*)(Bb + (size_t)r0 * 512 + kb + c0),
        (__attribute__((address_space(3))) uint32_t*)((char*)Bs + seg0 * 1024), 16, 0, 0);
    __builtin_amdgcn_global_load_lds(
        (const __attribute__((address_space(1))) uint32_t*)(Bb + (size_t)r1 * 512 + kb + c1),
        (__attribute__((address_space(3))) uint32_t*)((char*)Bs + (seg0 + 1) * 1024), 16, 0, 0);
    __syncthreads();

    short8v af[4], bfr[4];
    #pragma unroll
    for (int mi = 0; mi < 4; mi++) {
      const int rr = wr * 64 + mi * 16 + (lane & 15);
      af[mi] = *(const short8v*)((const char*)As + rr * 64 + (lane >> 4) * 16);
    }
    #pragma unroll
    for (int nj = 0; nj < 4; nj++) {
      const int rr = wc * 64 + nj * 16 + (lane & 15);
      bfr[nj] = *(const short8v*)((const char*)Bs + rr * 64 + (lane >> 4) * 16);
    }
    #pragma unroll
    for (int mi = 0; mi < 4; mi++)
      #pragma unroll
      for (int nj = 0; nj < 4; nj++)
        acc[mi][nj] = __builtin_amdgcn_mfma_f32_16x16x32_bf16(af[mi], bfr[nj], acc[mi][nj], 0, 0, 0);
    __syncthreads();
  }

  float* Cb = cost + (size_t)b * NN * NN + (size_t)(tm * 128) * NN + tn * 128;
  #pragma unroll
  for (int mi = 0; mi < 4; mi++)
    #pragma unroll
    for (int nj = 0; nj < 4; nj++)
      #pragma unroll
      for (int v = 0; v < 4; v++) {
        const int rr = wr * 64 + mi * 16 + (lane >> 4) * 4 + v;
        const int cc = wc * 64 + nj * 16 + (lane & 15);
        Cb[(size_t)rr * NN + cc] = 1.0f - acc[mi][nj][v];
      }
}

// ---------------- Kernel 3: DTW forward + backtrack + logsumexps ----------------
// One 64-lane wave per batch. Lane l owns cols [8l,8l+8). Skewed schedule:
// lane l processes row r at step t=r+l; boundary tc values flow via shfl_up.
// Decisions (2 bits/cell, reference tie-break diag>up>left) packed in LDS.
__global__ __launch_bounds__(64) void dtw_kernel(
    const float* __restrict__ cost, float* __restrict__ out)
{
  extern __shared__ char lds_raw[];
  uint16_t* dec  = (uint16_t*)lds_raw;              // [512*64] u16 = 64 KB
  uint16_t* rlo  = (uint16_t*)(lds_raw + 65536);    // [512]
  uint16_t* rhi  = (uint16_t*)(lds_raw + 66560);    // [512]
  float*  colpos = (float*)  (lds_raw + 67584);     // [512]

  const int l = threadIdx.x;
  const int b = blockIdx.x;
  const float* cg = cost + (size_t)b * NN * NN;
  const float* crow = cg + l * 8;

  float tprev[8], colsum[8];
  float4v bufa[4], bufb[4];
  #pragma unroll
  for (int c = 0; c < 8; c++) { tprev[c] = FINF; colsum[c] = 0.0f; }
  float prev_last = FINF, cur_last = FINF;

  // prologue: buffers u=0..3 <- rows (u-l), depth-4 prefetch pipeline
  #pragma unroll
  for (int u = 0; u < 4; u++) {
    const int r = u - l;
    if (r >= 0) {
      const float* p = crow + (size_t)r * NN;
      bufa[u] = *(const float4v*)p;
      bufb[u] = *(const float4v*)(p + 4);
    }
  }

  for (int t = 0; t < 576; t += 4) {
    #pragma unroll
    for (int u = 0; u < 4; u++) {
      const int tt = t + u;
      float sh_p = __shfl_up(prev_last, 1, 64);  // tc[r-1][8l-1] from lane l-1
      float sh_c = __shfl_up(cur_last, 1, 64);   // tc[r  ][8l-1] from lane l-1
      if (l == 0) { sh_p = FINF; sh_c = FINF; }
      const int r = tt - l;
      if (r >= 0 && r < NN) {
        float dcarry = sh_p, lcarry = sh_c;
        uint32_t word = 0;
        #pragma unroll
        for (int c = 0; c < 8; c++) {
          const float cst = (c < 4) ? bufa[u][c] : bufb[u][c & 3];
          const float up = tprev[c];
          float m3 = fminf(fminf(dcarry, up), lcarry);
          if (c == 0) { if ((r | l) == 0) m3 = 0.0f; }  // cell (0,0): tc = cost
          const float tn = cst + m3;
          // dec==0 iff diag==min3  <=>  a<=b && a<=c  (reference tie-break)
          const uint32_t dd = (m3 == dcarry) ? 0u : ((m3 == up) ? 1u : 2u);
          word |= dd << (2 * c);
          colsum[c] += cst;
          tprev[c] = tn;
          dcarry = up;
          lcarry = tn;
        }
        dec[r * 64 + l] = (uint16_t)word;
        prev_last = dcarry;   // old tprev[7] = tc[r-1][8l+7]
        cur_last  = lcarry;   // tc[r][8l+7]
      }
      const int rn = tt + 4 - l;  // refill this buffer for use 4 steps ahead
      if (rn >= 0 && rn < NN) {
        const float* p = crow + (size_t)rn * NN;
        bufa[u] = *(const float4v*)p;
        bufb[u] = *(const float4v*)(p + 4);
      }
    }
  }

  // ---- neg = logsumexp over column sums ----
  float mx = colsum[0];
  #pragma unroll
  for (int c = 1; c < 8; c++) mx = fmaxf(mx, colsum[c]);
  #pragma unroll
  for (int d = 1; d < 64; d <<= 1) mx = fmaxf(mx, __shfl_xor(mx, d, 64));
  float se = 0.f;
  #pragma unroll
  for (int c = 0; c < 8; c++) se += expf(colsum[c] - mx);
  #pragma unroll
  for (int d = 1; d < 64; d <<= 1) se += __shfl_xor(se, d, 64);
  const float neg = mx + logf(se);

  // ---- backtrack: record per-row contiguous column interval of the path ----
  for (int r = l; r < NN; r += 64) { rlo[r] = 1; rhi[r] = 0; colpos[r] = 0.0f; }
  __syncthreads();
  if (l == 0) {
    int i = NN - 1, j = NN - 1, hicur = NN - 1;
    const uint32_t* dec32 = (const uint32_t*)dec;
    while (i > 0 && j > 0) {
      const uint32_t w = dec32[i * 32 + (j >> 4)];
      const uint32_t dd = (w >> ((j & 15) * 2)) & 3u;
      if (dd == 2u) { j--; }           // left: stay in row
      else {
        rlo[i] = (uint16_t)j; rhi[i] = (uint16_t)hicur;  // leave row i
        i--;
        if (dd == 0u) j--;             // diag also moves left
        hicur = j;                     // entry column of new row
      }
    }
    rlo[i] = (uint16_t)j; rhi[i] = (uint16_t)hicur;      // pending row at exit
  }
  __syncthreads();
  // accumulate colpos[m] = sum_n cost*path (rows parallel across lanes)
  for (int r = l; r < NN; r += 64) {
    const int lo = rlo[r], hi = rhi[r];
    for (int j = lo; j <= hi; j++) atomicAdd(&colpos[j], cg[(size_t)r * NN + j]);
  }
  // reference always sets p[0,0]=1; add it if row-0 interval doesn't cover col 0
  if (l == 0 && rlo[0] != 0) atomicAdd(&colpos[0], cg[0]);
  __syncthreads();

  // ---- pos = logsumexp over colpos (zeros of unvisited columns included) ----
  float mv[8];
  float mx2 = -FINF;
  #pragma unroll
  for (int k = 0; k < 8; k++) { mv[k] = colpos[l + 64 * k]; mx2 = fmaxf(mx2, mv[k]); }
  #pragma unroll
  for (int d = 1; d < 64; d <<= 1) mx2 = fmaxf(mx2, __shfl_xor(mx2, d, 64));
  float se2 = 0.f;
  #pragma unroll
  for (int k = 0; k < 8; k++) se2 += expf(mv[k] - mx2);
  #pragma unroll
  for (int d = 1; d < 64; d <<= 1) se2 += __shfl_xor(se2, d, 64);
  const float pos = mx2 + logf(se2);

  if (l == 0) out[b] = pos - neg;
}

extern "C" void kernel_launch(void* const* d_in, const int* in_sizes, int n_in,
                              void* d_out, int out_size, void* d_ws, size_t ws_size,
                              hipStream_t stream)
{
  (void)in_sizes; (void)n_in; (void)out_size; (void)ws_size;
  const float* x = (const float*)d_in[0];
  const float* y = (const float*)d_in[1];
  float* out = (float*)d_out;
  char* ws = (char*)d_ws;
  uint16_t* xnb = (uint16_t*)ws;
  uint16_t* ynb = (uint16_t*)(ws + (size_t)16777216);
  float*   cost = (float*)  (ws + (size_t)33554432);

  // dtw uses 68 KB dynamic LDS (> 64 KB default cap) — opt in every call (idempotent, capture-safe)
  (void)hipFuncSetAttribute((const void*)dtw_kernel,
                            hipFuncAttributeMaxDynamicSharedMemorySize, 69632);

  norm_cast_kernel<<<16384, 256, 0, stream>>>(x, y, xnb, ynb);
  gemm_cost_kernel<<<1024, 256, 0, stream>>>(xnb, ynb, cost);
  dtw_kernel<<<64, 64, 69632, stream>>>(cost, out);
}

// Round 2
// 386.384 us; speedup vs baseline: 1.0253x; 1.0253x over previous
//
#include <hip/hip_runtime.h>
#include <hip/hip_bf16.h>
#include <stdint.h>

typedef __attribute__((ext_vector_type(8))) short short8v;     // 8 x bf16 (MFMA A/B frag)
typedef __attribute__((ext_vector_type(4))) float float4v;     // MFMA C/D frag / vec loads
typedef __attribute__((ext_vector_type(4))) unsigned short ushort4v;
typedef __attribute__((ext_vector_type(4))) unsigned int uint4v;

#define FINF __builtin_huge_valf()
#define BB 64
#define NN 512
#define DD 256
#define TT_SKEW 576   // skew rows: t = r + (j>>3) in [0, 511+63] -> pad to 576

// ws layout (bytes):
//   [0,        16777216)  xnb bf16 [B][N][D]
//   [16777216, 33554432)  ynb bf16 [B][N][D]
//   [33554432, 71303168)  cost_skew bf16 [B][576][512]  (element (r,j) at t=r+(j>>3), col j)

static __device__ __forceinline__ unsigned short f2bf(float f) {
  union { float f; uint32_t u; } a; a.f = f;
  uint32_t r = a.u + 0x7fffu + ((a.u >> 16) & 1u);   // RNE
  return (unsigned short)(r >> 16);
}
static __device__ __forceinline__ float bf2f(uint16_t v) {
  return __uint_as_float(((uint32_t)v) << 16);
}

// ---------------- Kernel 1: row-normalize + cast to bf16 ----------------
__global__ __launch_bounds__(256) void norm_cast_kernel(
    const float* __restrict__ x, const float* __restrict__ y,
    uint16_t* __restrict__ xnb, uint16_t* __restrict__ ynb)
{
  const int wave = threadIdx.x >> 6, lane = threadIdx.x & 63;
  const int row = blockIdx.x * 4 + wave;
  const float* src; uint16_t* dst;
  if (row < BB * NN) { src = x + (size_t)row * DD;            dst = xnb + (size_t)row * DD; }
  else               { src = y + (size_t)(row - BB*NN) * DD;  dst = ynb + (size_t)(row - BB*NN) * DD; }
  const float4v v = *(const float4v*)(src + lane * 4);
  float s = v[0]*v[0] + v[1]*v[1] + v[2]*v[2] + v[3]*v[3];
  #pragma unroll
  for (int d = 1; d < 64; d <<= 1) s += __shfl_xor(s, d, 64);
  const float inv = 1.0f / fmaxf(sqrtf(s), 1e-8f);
  ushort4v o;
  o[0] = f2bf(v[0] * inv); o[1] = f2bf(v[1] * inv);
  o[2] = f2bf(v[2] * inv); o[3] = f2bf(v[3] * inv);
  *(ushort4v*)(dst + lane * 4) = o;
}

// ---------------- Kernel 2: cost = 1 - xn·yn -> bf16 skewed layout ----------------
// 128x128 tile per block, 4 waves (2x2), BK=32, K=256. NT-GEMM, bf16 MFMA 16x16x32.
__global__ __launch_bounds__(256) void gemm_cost_kernel(
    const uint16_t* __restrict__ xnb, const uint16_t* __restrict__ ynb,
    uint16_t* __restrict__ skew)
{
  __shared__ uint16_t As[128 * 32];
  __shared__ uint16_t Bs[128 * 32];
  const int bid = blockIdx.x;
  const int b = bid >> 4, tm = (bid >> 2) & 3, tn = bid & 3;
  const int tid = threadIdx.x, wave = tid >> 6, lane = tid & 63;
  const int wr = wave >> 1, wc = wave & 1;

  const char* Ab = (const char*)(xnb + (size_t)b * NN * DD + (size_t)tm * 128 * DD);
  const char* Bb = (const char*)(ynb + (size_t)b * NN * DD + (size_t)tn * 128 * DD);

  float4v acc[4][4];
  #pragma unroll
  for (int i = 0; i < 4; i++)
    #pragma unroll
    for (int j = 0; j < 4; j++) acc[i][j] = (float4v){0.f, 0.f, 0.f, 0.f};

  const int seg0 = wave * 2;
  const int o0 = seg0 * 1024 + lane * 16;
  const int o1 = o0 + 1024;
  const int r0 = o0 >> 6, c0 = o0 & 63;
  const int r1 = o1 >> 6, c1 = o1 & 63;

  for (int kk = 0; kk < 8; kk++) {
    const int kb = kk * 64;
    __builtin_amdgcn_global_load_lds(
        (const __attribute__((address_space(1))) uint32_t*)(Ab + (size_t)r0 * 512 + kb + c0),
        (__attribute__((address_space(3))) uint32_t*)((char*)As + seg0 * 1024), 16, 0, 0);
    __builtin_amdgcn_global_load_lds(
        (const __attribute__((address_space(1))) uint32_t*)(Ab + (size_t)r1 * 512 + kb + c1),
        (__attribute__((address_space(3))) uint32_t*)((char*)As + (seg0 + 1) * 1024), 16, 0, 0);
    __builtin_amdgcn_global_load_lds(
        (const __attribute__((address_space(1))) uint32_t*)(Bb + (size_t)r0 * 512 + kb + c0),
        (__attribute__((address_space(3))) uint32_t*)((char*)Bs + seg0 * 1024), 16, 0, 0);
    __builtin_amdgcn_global_load_lds(
        (const __attribute__((address_space(1))) uint32_t*)(Bb + (size_t)r1 * 512 + kb + c1),
        (__attribute__((address_space(3))) uint32_t*)((char*)Bs + (seg0 + 1) * 1024), 16, 0, 0);
    __syncthreads();

    short8v af[4], bfr[4];
    #pragma unroll
    for (int mi = 0; mi < 4; mi++) {
      const int rr = wr * 64 + mi * 16 + (lane & 15);
      af[mi] = *(const short8v*)((const char*)As + rr * 64 + (lane >> 4) * 16);
    }
    #pragma unroll
    for (int nj = 0; nj < 4; nj++) {
      const int rr = wc * 64 + nj * 16 + (lane & 15);
      bfr[nj] = *(const short8v*)((const char*)Bs + rr * 64 + (lane >> 4) * 16);
    }
    #pragma unroll
    for (int mi = 0; mi < 4; mi++)
      #pragma unroll
      for (int nj = 0; nj < 4; nj++)
        acc[mi][nj] = __builtin_amdgcn_mfma_f32_16x16x32_bf16(af[mi], bfr[nj], acc[mi][nj], 0, 0, 0);
    __syncthreads();
  }

  uint16_t* Cb = skew + (size_t)b * TT_SKEW * NN;
  #pragma unroll
  for (int mi = 0; mi < 4; mi++)
    #pragma unroll
    for (int nj = 0; nj < 4; nj++) {
      const int cc = tn * 128 + wc * 64 + nj * 16 + (lane & 15);
      const int lg = cc >> 3;
      #pragma unroll
      for (int v = 0; v < 4; v++) {
        const int rr = tm * 128 + wr * 64 + mi * 16 + (lane >> 4) * 4 + v;
        Cb[(size_t)(rr + lg) * NN + cc] = f2bf(1.0f - acc[mi][nj][v]);
      }
    }
}

// ---------------- Kernel 3: DTW forward + backtrack + logsumexps ----------------
// One 64-lane wave per batch. Lane l owns cols [8l,8l+8). Skewed schedule:
// lane l processes row r at step t=r+l; per-step refill is one contiguous 1KB
// wave load from the skewed bf16 cost (depth-8 register prefetch).
// Inner 8-cell recurrence via min-plus prefix scan (u[c]=min(w[c],u[c-1])).
// Decisions (2b/cell, tie-break diag>up>left) packed 2 rows per u32 in LDS.
__global__ __launch_bounds__(64) void dtw_kernel(
    const uint16_t* __restrict__ skew, float* __restrict__ out)
{
  extern __shared__ char lds_raw[];
  uint16_t* dec  = (uint16_t*)lds_raw;              // [256][64] u32 = 64 KB (2 rows/u32)
  uint16_t* rlo  = (uint16_t*)(lds_raw + 65536);    // [512]
  uint16_t* rhi  = (uint16_t*)(lds_raw + 66560);    // [512]
  float*  colpos = (float*)  (lds_raw + 67584);     // [512]

  const int l = threadIdx.x;
  const int b = blockIdx.x;
  const uint16_t* csk = skew + (size_t)b * TT_SKEW * NN;

  float tprev[8], colsum[8];
  uint4v buf[8];
  #pragma unroll
  for (int c = 0; c < 8; c++) { tprev[c] = FINF; colsum[c] = 0.0f; }
  float prev_last = FINF, cur_last = FINF;

  // prologue: depth-8 prefetch of steps 0..7 (1KB/wave each, contiguous)
  #pragma unroll
  for (int u = 0; u < 8; u++)
    buf[u] = *(const uint4v*)(csk + (size_t)u * NN + l * 8);

  for (int t = 0; t < TT_SKEW; t += 8) {
    #pragma unroll
    for (int u = 0; u < 8; u++) {
      const int tt = t + u;
      float sh_p = __shfl_up(prev_last, 1, 64);  // tc[r-1][8l-1] from lane l-1
      float sh_c = __shfl_up(cur_last, 1, 64);   // tc[r  ][8l-1] from lane l-1
      if (l == 0) { sh_p = FINF; sh_c = (tt == 0) ? 0.0f : FINF; }
      const int r = tt - l;
      if (r >= 0 && r < NN) {
        float cst[8], S[8];
        #pragma unroll
        for (int k = 0; k < 4; k++) {
          const uint32_t wv = buf[u][k];
          cst[2*k]   = __uint_as_float(wv << 16);
          cst[2*k+1] = __uint_as_float(wv & 0xFFFF0000u);
        }
        S[0] = cst[0];
        #pragma unroll
        for (int c = 1; c < 8; c++) S[c] = S[c-1] + cst[c];
        float dcp[8];
        dcp[0] = sh_p;
        #pragma unroll
        for (int c = 1; c < 8; c++) dcp[c] = tprev[c-1];
        float mu[8], w8[8];
        #pragma unroll
        for (int c = 0; c < 8; c++) mu[c] = fminf(dcp[c], tprev[c]);
        w8[0] = mu[0];
        #pragma unroll
        for (int c = 1; c < 8; c++) w8[c] = mu[c] - S[c-1];
        float uu[8];
        uu[0] = fminf(w8[0], sh_c);
        #pragma unroll
        for (int c = 1; c < 8; c++) uu[c] = fminf(w8[c], uu[c-1]);
        float tn[8];
        #pragma unroll
        for (int c = 0; c < 8; c++) tn[c] = uu[c] + S[c];
        float lc[8];
        lc[0] = sh_c;
        #pragma unroll
        for (int c = 1; c < 8; c++) lc[c] = tn[c-1];
        uint32_t word = 0;
        #pragma unroll
        for (int c = 0; c < 8; c++) {
          // argmin with reference tie-break diag > up > left (exact comparisons)
          const bool e0 = (dcp[c] <= tprev[c]) && (dcp[c] <= lc[c]);
          const uint32_t dd = e0 ? 0u : ((tprev[c] <= lc[c]) ? 1u : 2u);
          word |= dd << (2 * c);
          colsum[c] += cst[c];
        }
        dec[(r >> 1) * 128 + 2 * l + (r & 1)] = (uint16_t)word;
        prev_last = tprev[7];
        #pragma unroll
        for (int c = 0; c < 8; c++) tprev[c] = tn[c];
        cur_last = tn[7];
      }
      const int tnx = tt + 8;
      if (tnx < TT_SKEW)
        buf[u] = *(const uint4v*)(csk + (size_t)tnx * NN + l * 8);
    }
  }

  // ---- neg = logsumexp over column sums ----
  float mx = colsum[0];
  #pragma unroll
  for (int c = 1; c < 8; c++) mx = fmaxf(mx, colsum[c]);
  #pragma unroll
  for (int d = 1; d < 64; d <<= 1) mx = fmaxf(mx, __shfl_xor(mx, d, 64));
  float se = 0.f;
  #pragma unroll
  for (int c = 0; c < 8; c++) se += expf(colsum[c] - mx);
  #pragma unroll
  for (int d = 1; d < 64; d <<= 1) se += __shfl_xor(se, d, 64);
  const float neg = mx + logf(se);

  // ---- backtrack: per-row contiguous column interval of the path ----
  for (int r = l; r < NN; r += 64) { rlo[r] = 1; rhi[r] = 0; colpos[r] = 0.0f; }
  __syncthreads();
  if (l == 0) {
    int i = NN - 1, j = NN - 1, hicur = NN - 1;
    const uint32_t* dec32 = (const uint32_t*)dec;
    int cidx = -1; uint32_t cw = 0;
    while (i > 0 && j > 0) {
      const int widx = (i >> 1) * 64 + (j >> 3);
      if (widx != cidx) { cw = dec32[widx]; cidx = widx; }
      const uint32_t dd = (cw >> (((i & 1) << 4) + ((j & 7) << 1))) & 3u;
      if (dd == 2u) { j--; }           // left: stay in row
      else {
        rlo[i] = (uint16_t)j; rhi[i] = (uint16_t)hicur;  // leave row i
        i--;
        if (dd == 0u) j--;             // diag also moves left
        hicur = j;                     // entry column of new row
      }
    }
    rlo[i] = (uint16_t)j; rhi[i] = (uint16_t)hicur;      // pending row at exit
  }
  __syncthreads();
  // colpos[m] = sum_n cost*path (rows parallel across lanes; skew-layout reads)
  for (int r = l; r < NN; r += 64) {
    const int lo = rlo[r], hi = rhi[r];
    for (int j = lo; j <= hi; j++) {
      const float cv = bf2f(csk[(size_t)(r + (j >> 3)) * NN + j]);
      atomicAdd(&colpos[j], cv);
    }
  }
  // reference always sets p[0,0]=1
  if (l == 0 && rlo[0] != 0) atomicAdd(&colpos[0], bf2f(csk[0]));
  __syncthreads();

  // ---- pos = logsumexp over colpos ----
  float mv[8];
  float mx2 = -FINF;
  #pragma unroll
  for (int k = 0; k < 8; k++) { mv[k] = colpos[l + 64 * k]; mx2 = fmaxf(mx2, mv[k]); }
  #pragma unroll
  for (int d = 1; d < 64; d <<= 1) mx2 = fmaxf(mx2, __shfl_xor(mx2, d, 64));
  float se2 = 0.f;
  #pragma unroll
  for (int k = 0; k < 8; k++) se2 += expf(mv[k] - mx2);
  #pragma unroll
  for (int d = 1; d < 64; d <<= 1) se2 += __shfl_xor(se2, d, 64);
  const float pos = mx2 + logf(se2);

  if (l == 0) out[b] = pos - neg;
}

extern "C" void kernel_launch(void* const* d_in, const int* in_sizes, int n_in,
                              void* d_out, int out_size, void* d_ws, size_t ws_size,
                              hipStream_t stream)
{
  (void)in_sizes; (void)n_in; (void)out_size; (void)ws_size;
  const float* x = (const float*)d_in[0];
  const float* y = (const float*)d_in[1];
  float* out = (float*)d_out;
  char* ws = (char*)d_ws;
  uint16_t* xnb  = (uint16_t*)ws;
  uint16_t* ynb  = (uint16_t*)(ws + (size_t)16777216);
  uint16_t* skew = (uint16_t*)(ws + (size_t)33554432);

  (void)hipFuncSetAttribute((const void*)dtw_kernel,
                            hipFuncAttributeMaxDynamicSharedMemorySize, 69632);

  norm_cast_kernel<<<16384, 256, 0, stream>>>(x, y, xnb, ynb);
  gemm_cost_kernel<<<1024, 256, 0, stream>>>(xnb, ynb, skew);
  dtw_kernel<<<64, 64, 69632, stream>>>(skew, out);
}